// Round 18
// baseline (477.387 us; speedup 1.0000x reference)
//
#include <hip/hip_runtime.h>

#define BB 8
#define TT 2048
#define DD 64
#define HH 1024
#define OO 16
#define NGRP 16
#define RB 16          // row-blocks per sub-group
#define CHSG 16        // chains per sub-group (2 sub-groups -> 32 chains/group)
#define CHUNK 64
#define WASH 32
#define STEPS (CHUNK + WASH)   // 96
#define ZPS 20         // zp stride: 2-way banks (free) on write AND finalize read

typedef __attribute__((ext_vector_type(8))) short short8;
typedef __attribute__((ext_vector_type(4))) float f32x4;

// ws layout (f32 units) — same 70 MB envelope as r15/r17 (proven to fit)
#define WS_FLAGS 0                        // [grp][half][pb][pw] x32 u32 = 131072 (262144 reserved)
#define WS_HX    262144                   // [grp][half][par][ch][HH] bf16 = 524288 f32
#define WS_UPROJ (WS_HX + 524288)         // [b][t][HH] bf16 = 8388608 f32
#define WS_PART  (WS_UPROJ + 8388608)     // [grp][rb][TT][OO] f32 = 8388608

#define FLAG_IDX(g, h, pb, pw) (((((g)*2 + (h)) * RB + (pb)) * 8 + (pw)) * 32)

__device__ __forceinline__ unsigned short f2bf(float x) {
  union { float f; unsigned u; } v; v.f = x;
  unsigned r = v.u + 0x7FFF + ((v.u >> 16) & 1);   // RNE
  return (unsigned short)(r >> 16);
}
__device__ __forceinline__ float bf2f(unsigned short h) {
  union { unsigned u; float f; } v; v.u = ((unsigned)h) << 16; return v.f;
}

// proven r11 protocol: ALL exchange ops sc0 sc1 (served at the coherence point)
__device__ __forceinline__ uint4 ld_cohx4(const void* p) {
  uint4 r;
  asm volatile("global_load_dwordx4 %0, %1, off sc0 sc1" : "=&v"(r) : "v"(p));
  return r;
}
__device__ __forceinline__ void st_coh(unsigned* p, unsigned v) {
  asm volatile("global_store_dword %0, %1, off sc0 sc1" :: "v"(p), "v"(v) : "memory");
}
__device__ __forceinline__ unsigned ld_flag(const unsigned* p) {
  unsigned r;
  asm volatile("global_load_dword %0, %1, off sc0 sc1\n\ts_waitcnt vmcnt(0)"
               : "=&v"(r) : "v"(p) : "memory");
  return r;
}

__device__ __forceinline__ short8 ld_bf16x8(const float* p) {
  float4 v0 = *(const float4*)p;
  float4 v1 = *(const float4*)(p + 4);
  short8 r;
  r[0] = (short)f2bf(v0.x); r[1] = (short)f2bf(v0.y);
  r[2] = (short)f2bf(v0.z); r[3] = (short)f2bf(v0.w);
  r[4] = (short)f2bf(v1.x); r[5] = (short)f2bf(v1.y);
  r[6] = (short)f2bf(v1.z); r[7] = (short)f2bf(v1.w);
  return r;
}

// prep GEMM: up[bt][row] = w_in[row,:] . u[bt,:]  (M=16384, N=1024, K=64, MFMA)
__global__ __launch_bounds__(256) void uproj_kernel(
    const float* __restrict__ u, const float* __restrict__ w_in,
    unsigned short* __restrict__ up) {
  const int tid = threadIdx.x;
  const int lane = tid & 63;
  const int wv = tid >> 6;
  const int lm = lane & 15;
  const int l4 = lane >> 4;
  const int bt0 = blockIdx.x * 64;

  short8 A[4][2];
#pragma unroll
  for (int btt = 0; btt < 4; ++btt)
#pragma unroll
    for (int kt = 0; kt < 2; ++kt)
      A[btt][kt] = ld_bf16x8(u + (size_t)(bt0 + btt * 16 + lm) * DD + kt * 32 + l4 * 8);

#pragma unroll 1
  for (int rt = wv; rt < 64; rt += 4) {
    const float* wp = w_in + (size_t)(rt * 16 + lm) * DD + l4 * 8;
    short8 B0 = ld_bf16x8(wp);
    short8 B1 = ld_bf16x8(wp + 32);
#pragma unroll
    for (int btt = 0; btt < 4; ++btt) {
      f32x4 acc = (f32x4){0.f, 0.f, 0.f, 0.f};
      acc = __builtin_amdgcn_mfma_f32_16x16x32_bf16(A[btt][0], B0, acc, 0, 0, 0);
      acc = __builtin_amdgcn_mfma_f32_16x16x32_bf16(A[btt][1], B1, acc, 0, 0, 0);
#pragma unroll
      for (int j = 0; j < 4; ++j) {
        int bt = bt0 + btt * 16 + l4 * 4 + j;
        up[(size_t)bt * HH + rt * 16 + lm] = f2bf(acc[j]);
      }
    }
  }
}

__global__ __launch_bounds__(512, 4) void esn_kernel(
    const float* __restrict__ w, const float* __restrict__ w_bias,
    const float* __restrict__ w_out, float* __restrict__ ws)
{
  __shared__ float zp_sh[8 * 64 * ZPS];  // [wave][row*ZPS + ch]  (40 KB)
  __shared__ float hn_sh[64 * 17];       // [row*17 + ch]
  __shared__ float wout_sh[64 * 17];     // [row*17 + o]

  const int tid = threadIdx.x;
  const int lane = tid & 63;
  const int rg = tid >> 6;            // wave 0..7, k-slice [rg*128, rg*128+128)
  const int lm = lane & 15;
  const int l4 = lane >> 4;
  const int bid = blockIdx.x;
  const int grp = bid & 15;           // group = dir*8 + b
  const int rb = (bid >> 4) & 15;     // row-block: rows [rb*64, rb*64+64)
  const int half = bid >> 8;          // sub-group 0/1 (chains half*16..+16)
  const int dir = grp >> 3;
  const int b = grp & 7;
  const int row0 = rb * 64;

  unsigned* flags = (unsigned*)ws;
  unsigned short* hx = (unsigned short*)(ws + WS_HX);
  const unsigned short* uproj = (const unsigned short*)(ws + WS_UPROJ);
  float* partial = ws + WS_PART;

  // ---- A fragments, hi-only bf16: rows row0+mt*16+lm, k=(rg*4+kt)*32+l4*8+j
  short8 Ahi[4][4];
#pragma unroll
  for (int mt = 0; mt < 4; ++mt) {
#pragma unroll
    for (int kt = 0; kt < 4; ++kt)
      Ahi[mt][kt] = ld_bf16x8(
          w + (size_t)(row0 + mt * 16 + lm) * HH + (rg * 4 + kt) * 32 + l4 * 8);
  }

  for (int idx = tid; idx < 1024; idx += 512) {
    int r = idx >> 4, o = idx & 15;
    wout_sh[r * 17 + o] = w_out[(size_t)(1 + dir * HH + row0 + r) * OO + o];
  }

  // finalize mapping: thread -> chain ch, rows 2q2, 2q2+1
  const int ch = tid & 15;
  const int q2 = tid >> 4;            // 0..31
  const float bias0 = w_bias[row0 + 2 * q2];
  const float bias1 = w_bias[row0 + 2 * q2 + 1];
  const int cc_g = half * CHSG + ch;
  int ts_f = cc_g * CHUNK - WASH; if (ts_f < 0) ts_f = 0;
  float hp0 = 0.f, hp1 = 0.f;
  __syncthreads();

#pragma unroll 1
  for (int i = 0; i < STEPS; ++i) {
    const int par = i & 1;
    const unsigned short* hb_r =
        hx + ((size_t)((grp * 2 + half) * 2 + par) * CHSG + lm) * HH;

    // ---- uproj load early (plain cached; latency hides under poll+MFMA)
    int tau_f = ts_f + i;
    int t_u = dir ? (TT - 1 - tau_f) : tau_f;
    unsigned up = *(const unsigned*)(uproj + (size_t)(b * TT + t_u) * HH + row0 + 2 * q2);

    // ---- poll: 16 producer-WAVE flags (2 blocks x 8 waves), lanes 0-15
    if (i > 0) {
      const unsigned tg = (unsigned)i;
      unsigned v;
      do {
        v = 0xFFFFFFFFu;
        if (lane < 16)
          v = ld_flag(flags + FLAG_IDX(grp, half, 2 * rg + (lane >> 3), lane & 7));
      } while (!__all(v >= tg));
      asm volatile("" ::: "memory");
    }

    // ---- B loads: own k-slice, 4 coherent dwordx4 (hi-only bf16 h)
    uint4 Bv[4];
#pragma unroll
    for (int kt = 0; kt < 4; ++kt)
      Bv[kt] = ld_cohx4(hb_r + (rg * 4 + kt) * 32 + l4 * 8);
    asm volatile("s_waitcnt vmcnt(0)" ::: "memory");
    __builtin_amdgcn_sched_barrier(0);

    f32x4 acc[4];
#pragma unroll
    for (int mt = 0; mt < 4; ++mt) acc[mt] = (f32x4){0.f, 0.f, 0.f, 0.f};
#pragma unroll
    for (int kt = 0; kt < 4; ++kt) {
      short8 bh = *(short8*)&Bv[kt];
#pragma unroll
      for (int mt = 0; mt < 4; ++mt)
        acc[mt] = __builtin_amdgcn_mfma_f32_16x16x32_bf16(Ahi[mt][kt], bh, acc[mt], 0, 0, 0);
    }

    // ---- per-wave K-partials to LDS (stride 20: 2-way banks, free)
#pragma unroll
    for (int mt = 0; mt < 4; ++mt)
#pragma unroll
      for (int j = 0; j < 4; ++j)
        zp_sh[rg * (64 * ZPS) + (mt * 16 + l4 * 4 + j) * ZPS + lm] = acc[mt][j];
    __syncthreads();

    // ---- finalize rows 2q2, 2q2+1 of chain ch
    float z0 = bias0 + bf2f((unsigned short)(up & 0xFFFFu));
    float z1 = bias1 + bf2f((unsigned short)(up >> 16));
#pragma unroll
    for (int g2 = 0; g2 < 8; ++g2) {
      z0 += zp_sh[g2 * (64 * ZPS) + (2 * q2) * ZPS + ch];
      z1 += zp_sh[g2 * (64 * ZPS) + (2 * q2 + 1) * ZPS + ch];
    }
    float e0 = __expf(2.f * z0), e1 = __expf(2.f * z1);
    float th0 = 1.f - 2.f * __builtin_amdgcn_rcpf(e0 + 1.f);
    float th1 = 1.f - 2.f * __builtin_amdgcn_rcpf(e1 + 1.f);
    hp0 = 0.1f * hp0 + 0.9f * th0;
    hp1 = 0.1f * hp1 + 0.9f * th1;
    hn_sh[(2 * q2) * 17 + ch] = hp0;
    hn_sh[(2 * q2 + 1) * 17 + ch] = hp1;
    unsigned pv = (unsigned)f2bf(hp0) | ((unsigned)f2bf(hp1) << 16);
    unsigned short* hw =
        hx + ((size_t)((grp * 2 + half) * 2 + (par ^ 1)) * CHSG + ch) * HH;
    st_coh((unsigned*)(hw + row0 + 2 * q2), pv);
    asm volatile("s_waitcnt vmcnt(0)" ::: "memory");   // THIS wave's h at L3
    // per-wave early flag: certifies rows [8rg, 8rg+8) of all 16 chains
    if (lane == 0)
      st_coh(flags + FLAG_IDX(grp, half, rb, rg), (unsigned)(i + 1));
    __syncthreads();   // hn_sh complete for readout (after flag: off crit path)

    // ---- readout: 2 chains per wave, direct writes (disjoint t)
#pragma unroll
    for (int cidx = 0; cidx < 2; ++cidx) {
      int cc = rg * 2 + cidx;               // local chain
      int cg = half * CHSG + cc;            // global chain
      int ts = cg * CHUNK - WASH; if (ts < 0) ts = 0;
      int tau = ts + i;
      int rel = tau - cg * CHUNK;
      if (rel >= 0 && rel < CHUNK) {
        int t_out = dir ? (TT - 1 - tau) : tau;
        float s = 0.f;
#pragma unroll
        for (int j = 0; j < 16; ++j)
          s += hn_sh[(l4 * 16 + j) * 17 + cc] * wout_sh[(l4 * 16 + j) * 17 + lm];
        s += __shfl_xor(s, 16);
        s += __shfl_xor(s, 32);
        if (lane < 16)
          partial[((size_t)(grp * RB + rb) * TT + t_out) * OO + lm] = s;
      }
    }
  }
}

__global__ __launch_bounds__(256) void combine_kernel(
    const float* __restrict__ w_out, const float* __restrict__ partial,
    float* __restrict__ out)
{
  int idx = blockIdx.x * 256 + threadIdx.x;   // (b*2048+t)*16+o
  int o = idx & 15;
  int bt = idx >> 4;
  int b_ = bt >> 11;
  int t_ = bt & 2047;
  float s = w_out[o];   // bias row
#pragma unroll 1
  for (int dir = 0; dir < 2; ++dir)
#pragma unroll
    for (int g = 0; g < 16; ++g)
      s += partial[((size_t)((dir * 8 + b_) * 16 + g) * TT + t_) * OO + o];
  out[idx] = s;
}

extern "C" void kernel_launch(void* const* d_in, const int* in_sizes, int n_in,
                              void* d_out, int out_size, void* d_ws, size_t ws_size,
                              hipStream_t stream) {
  (void)in_sizes; (void)n_in; (void)out_size; (void)ws_size;
  const float* u      = (const float*)d_in[0];
  const float* w      = (const float*)d_in[1];
  const float* w_in   = (const float*)d_in[2];
  const float* w_bias = (const float*)d_in[3];
  const float* w_out  = (const float*)d_in[4];
  float* out = (float*)d_out;
  float* ws  = (float*)d_ws;

  // zero flags + bf16 h double buffers each replay (partial fully overwritten)
  (void)hipMemsetAsync(d_ws, 0, (size_t)(WS_HX + 524288) * 4, stream);

  uproj_kernel<<<dim3(256), dim3(256), 0, stream>>>(
      u, w_in, (unsigned short*)(ws + WS_UPROJ));
  esn_kernel<<<dim3(512), dim3(512), 0, stream>>>(w, w_bias, w_out, ws);
  combine_kernel<<<dim3((BB * TT * OO) / 256), dim3(256), 0, stream>>>(
      w_out, ws + WS_PART, out);
}

// Round 19
// 415.769 us; speedup vs baseline: 1.1482x; 1.1482x over previous
//
#include <hip/hip_runtime.h>

#define BB 8
#define TT 2048
#define DD 64
#define HH 1024
#define OO 16
#define NGRP 16
#define RB 16          // row-blocks per sub-group
#define CHSG 16        // chains per sub-group (2 sub-groups -> 32 chains/group)
#define CHUNK 64
#define WASH 32
#define STEPS (CHUNK + WASH)   // 96
#define ZPS 20         // zp stride: 2-way banks (free) on write AND finalize read

typedef __attribute__((ext_vector_type(8))) short short8;
typedef __attribute__((ext_vector_type(4))) float f32x4;

// ws layout (f32 units)
#define WS_FLAGS 0                        // [grp][half][pb][cb] x32 u32 = 262144
#define WS_HX    262144                   // [grp][half][par][ch][HH] bf16 = 524288 f32
#define WS_UPROJ (WS_HX + 524288)         // [b][t][HH] bf16 = 8388608 f32
#define WS_PART  (WS_UPROJ + 8388608)     // [grp][rb][TT][OO] f32 = 8388608

#define FLAG_IDX(g, h, pb, cb) (((((g)*2 + (h)) * RB + (pb)) * RB + (cb)) * 32)

__device__ __forceinline__ unsigned short f2bf(float x) {
  union { float f; unsigned u; } v; v.f = x;
  unsigned r = v.u + 0x7FFF + ((v.u >> 16) & 1);   // RNE
  return (unsigned short)(r >> 16);
}
__device__ __forceinline__ float bf2f(unsigned short h) {
  union { unsigned u; float f; } v; v.u = ((unsigned)h) << 16; return v.f;
}

// proven r11 protocol: ALL exchange ops sc0 sc1 (served at the coherence point)
__device__ __forceinline__ uint4 ld_cohx4(const void* p) {
  uint4 r;
  asm volatile("global_load_dwordx4 %0, %1, off sc0 sc1" : "=&v"(r) : "v"(p));
  return r;
}
__device__ __forceinline__ void st_coh(unsigned* p, unsigned v) {
  asm volatile("global_store_dword %0, %1, off sc0 sc1" :: "v"(p), "v"(v) : "memory");
}
__device__ __forceinline__ unsigned ld_flag(const unsigned* p) {
  unsigned r;
  asm volatile("global_load_dword %0, %1, off sc0 sc1\n\ts_waitcnt vmcnt(0)"
               : "=&v"(r) : "v"(p) : "memory");
  return r;
}

__device__ __forceinline__ short8 ld_bf16x8(const float* p) {
  float4 v0 = *(const float4*)p;
  float4 v1 = *(const float4*)(p + 4);
  short8 r;
  r[0] = (short)f2bf(v0.x); r[1] = (short)f2bf(v0.y);
  r[2] = (short)f2bf(v0.z); r[3] = (short)f2bf(v0.w);
  r[4] = (short)f2bf(v1.x); r[5] = (short)f2bf(v1.y);
  r[6] = (short)f2bf(v1.z); r[7] = (short)f2bf(v1.w);
  return r;
}

// prep GEMM: up[bt][row] = w_in[row,:] . u[bt,:]  (M=16384, N=1024, K=64, MFMA)
__global__ __launch_bounds__(256) void uproj_kernel(
    const float* __restrict__ u, const float* __restrict__ w_in,
    unsigned short* __restrict__ up) {
  const int tid = threadIdx.x;
  const int lane = tid & 63;
  const int wv = tid >> 6;
  const int lm = lane & 15;
  const int l4 = lane >> 4;
  const int bt0 = blockIdx.x * 64;

  short8 A[4][2];
#pragma unroll
  for (int btt = 0; btt < 4; ++btt)
#pragma unroll
    for (int kt = 0; kt < 2; ++kt)
      A[btt][kt] = ld_bf16x8(u + (size_t)(bt0 + btt * 16 + lm) * DD + kt * 32 + l4 * 8);

#pragma unroll 1
  for (int rt = wv; rt < 64; rt += 4) {
    const float* wp = w_in + (size_t)(rt * 16 + lm) * DD + l4 * 8;
    short8 B0 = ld_bf16x8(wp);
    short8 B1 = ld_bf16x8(wp + 32);
#pragma unroll
    for (int btt = 0; btt < 4; ++btt) {
      f32x4 acc = (f32x4){0.f, 0.f, 0.f, 0.f};
      acc = __builtin_amdgcn_mfma_f32_16x16x32_bf16(A[btt][0], B0, acc, 0, 0, 0);
      acc = __builtin_amdgcn_mfma_f32_16x16x32_bf16(A[btt][1], B1, acc, 0, 0, 0);
#pragma unroll
      for (int j = 0; j < 4; ++j) {
        int bt = bt0 + btt * 16 + l4 * 4 + j;
        up[(size_t)bt * HH + rt * 16 + lm] = f2bf(acc[j]);
      }
    }
  }
}

__global__ __launch_bounds__(512, 4) void esn_kernel(
    const float* __restrict__ w, const float* __restrict__ w_bias,
    const float* __restrict__ w_out, float* __restrict__ ws)
{
  __shared__ float zp_sh[8 * 64 * ZPS];  // [wave][row*ZPS + ch]  (40 KB)
  __shared__ float hn_sh[64 * 17];       // [row*17 + ch]
  __shared__ float wout_sh[64 * 17];     // [row*17 + o]

  const int tid = threadIdx.x;
  const int lane = tid & 63;
  const int rg = tid >> 6;            // wave 0..7, k-slice [rg*128, rg*128+128)
  const int lm = lane & 15;
  const int l4 = lane >> 4;
  const int bid = blockIdx.x;
  const int grp = bid & 15;           // group = dir*8 + b
  const int rb = (bid >> 4) & 15;     // row-block: rows [rb*64, rb*64+64)
  const int half = bid >> 8;          // sub-group 0/1 (chains half*16..+16)
  const int dir = grp >> 3;
  const int b = grp & 7;
  const int row0 = rb * 64;

  unsigned* flags = (unsigned*)ws;
  unsigned short* hx = (unsigned short*)(ws + WS_HX);
  const unsigned short* uproj = (const unsigned short*)(ws + WS_UPROJ);
  float* partial = ws + WS_PART;

  // ---- A fragments, hi-only bf16: rows row0+mt*16+lm, k=(rg*4+kt)*32+l4*8+j
  short8 Ahi[4][4];
#pragma unroll
  for (int mt = 0; mt < 4; ++mt) {
#pragma unroll
    for (int kt = 0; kt < 4; ++kt)
      Ahi[mt][kt] = ld_bf16x8(
          w + (size_t)(row0 + mt * 16 + lm) * HH + (rg * 4 + kt) * 32 + l4 * 8);
  }

  for (int idx = tid; idx < 1024; idx += 512) {
    int r = idx >> 4, o = idx & 15;
    wout_sh[r * 17 + o] = w_out[(size_t)(1 + dir * HH + row0 + r) * OO + o];
  }

  // finalize mapping: thread -> chain ch, rows 2q2, 2q2+1
  const int ch = tid & 15;
  const int q2 = tid >> 4;            // 0..31
  const float bias0 = w_bias[row0 + 2 * q2];
  const float bias1 = w_bias[row0 + 2 * q2 + 1];
  const int cc_g = half * CHSG + ch;
  int ts_f = cc_g * CHUNK - WASH; if (ts_f < 0) ts_f = 0;
  float hp0 = 0.f, hp1 = 0.f;
  __syncthreads();

#pragma unroll 1
  for (int i = 0; i < STEPS; ++i) {
    const int par = i & 1;
    const unsigned short* hb_r =
        hx + ((size_t)((grp * 2 + half) * 2 + par) * CHSG + lm) * HH;

    // ---- uproj load early (plain cached; latency hides under poll+MFMA)
    int tau_f = ts_f + i;
    int t_u = dir ? (TT - 1 - tau_f) : tau_f;
    unsigned up = *(const unsigned*)(uproj + (size_t)(b * TT + t_u) * HH + row0 + 2 * q2);

    // ---- per-wave producer-pair poll (r17-proven): blocks 2rg, 2rg+1 of own half
    if (i > 0) {
      const unsigned tg = (unsigned)i;
      unsigned v;
      do {
        v = 0xFFFFFFFFu;
        if (lane < 2)
          v = ld_flag(flags + FLAG_IDX(grp, half, 2 * rg + lane, rb));
      } while (!__all(v >= tg));
      asm volatile("" ::: "memory");
    }

    // ---- B loads: own k-slice, 4 coherent dwordx4 (hi-only bf16 h)
    uint4 Bv[4];
#pragma unroll
    for (int kt = 0; kt < 4; ++kt)
      Bv[kt] = ld_cohx4(hb_r + (rg * 4 + kt) * 32 + l4 * 8);
    asm volatile("s_waitcnt vmcnt(0)" ::: "memory");
    __builtin_amdgcn_sched_barrier(0);

    f32x4 acc[4];
#pragma unroll
    for (int mt = 0; mt < 4; ++mt) acc[mt] = (f32x4){0.f, 0.f, 0.f, 0.f};
#pragma unroll
    for (int kt = 0; kt < 4; ++kt) {
      short8 bh = *(short8*)&Bv[kt];
#pragma unroll
      for (int mt = 0; mt < 4; ++mt)
        acc[mt] = __builtin_amdgcn_mfma_f32_16x16x32_bf16(Ahi[mt][kt], bh, acc[mt], 0, 0, 0);
    }

    // ---- per-wave K-partials to LDS (stride 20: 2-way banks, free)
#pragma unroll
    for (int mt = 0; mt < 4; ++mt)
#pragma unroll
      for (int j = 0; j < 4; ++j)
        zp_sh[rg * (64 * ZPS) + (mt * 16 + l4 * 4 + j) * ZPS + lm] = acc[mt][j];
    __syncthreads();

    // ---- finalize rows 2q2, 2q2+1 of chain ch
    float z0 = bias0 + bf2f((unsigned short)(up & 0xFFFFu));
    float z1 = bias1 + bf2f((unsigned short)(up >> 16));
#pragma unroll
    for (int g2 = 0; g2 < 8; ++g2) {
      z0 += zp_sh[g2 * (64 * ZPS) + (2 * q2) * ZPS + ch];
      z1 += zp_sh[g2 * (64 * ZPS) + (2 * q2 + 1) * ZPS + ch];
    }
    float e0 = __expf(2.f * z0), e1 = __expf(2.f * z1);
    float th0 = 1.f - 2.f * __builtin_amdgcn_rcpf(e0 + 1.f);
    float th1 = 1.f - 2.f * __builtin_amdgcn_rcpf(e1 + 1.f);
    hp0 = 0.1f * hp0 + 0.9f * th0;
    hp1 = 0.1f * hp1 + 0.9f * th1;
    hn_sh[(2 * q2) * 17 + ch] = hp0;
    hn_sh[(2 * q2 + 1) * 17 + ch] = hp1;
    unsigned pv = (unsigned)f2bf(hp0) | ((unsigned)f2bf(hp1) << 16);
    unsigned short* hw =
        hx + ((size_t)((grp * 2 + half) * 2 + (par ^ 1)) * CHSG + ch) * HH;
    st_coh((unsigned*)(hw + row0 + 2 * q2), pv);
    asm volatile("s_waitcnt vmcnt(0)" ::: "memory");   // h at coherence point
    __syncthreads();                                   // all waves' h committed
    if (tid < 16)   // replicated flag: one line per consumer block (r17-proven)
      st_coh(flags + FLAG_IDX(grp, half, rb, tid), (unsigned)(i + 1));

    // ---- readout: 2 chains per wave, direct writes (disjoint t)
#pragma unroll
    for (int cidx = 0; cidx < 2; ++cidx) {
      int cc = rg * 2 + cidx;               // local chain
      int cg = half * CHSG + cc;            // global chain
      int ts = cg * CHUNK - WASH; if (ts < 0) ts = 0;
      int tau = ts + i;
      int rel = tau - cg * CHUNK;
      if (rel >= 0 && rel < CHUNK) {
        int t_out = dir ? (TT - 1 - tau) : tau;
        float s = 0.f;
#pragma unroll
        for (int j = 0; j < 16; ++j)
          s += hn_sh[(l4 * 16 + j) * 17 + cc] * wout_sh[(l4 * 16 + j) * 17 + lm];
        s += __shfl_xor(s, 16);
        s += __shfl_xor(s, 32);
        if (lane < 16)
          partial[((size_t)(grp * RB + rb) * TT + t_out) * OO + lm] = s;
      }
    }
  }
}

__global__ __launch_bounds__(256) void combine_kernel(
    const float* __restrict__ w_out, const float* __restrict__ partial,
    float* __restrict__ out)
{
  int idx = blockIdx.x * 256 + threadIdx.x;   // (b*2048+t)*16+o
  int o = idx & 15;
  int bt = idx >> 4;
  int b_ = bt >> 11;
  int t_ = bt & 2047;
  float s = w_out[o];   // bias row
#pragma unroll 1
  for (int dir = 0; dir < 2; ++dir)
#pragma unroll
    for (int g = 0; g < 16; ++g)
      s += partial[((size_t)((dir * 8 + b_) * 16 + g) * TT + t_) * OO + o];
  out[idx] = s;
}

extern "C" void kernel_launch(void* const* d_in, const int* in_sizes, int n_in,
                              void* d_out, int out_size, void* d_ws, size_t ws_size,
                              hipStream_t stream) {
  (void)in_sizes; (void)n_in; (void)out_size; (void)ws_size;
  const float* u      = (const float*)d_in[0];
  const float* w      = (const float*)d_in[1];
  const float* w_in   = (const float*)d_in[2];
  const float* w_bias = (const float*)d_in[3];
  const float* w_out  = (const float*)d_in[4];
  float* out = (float*)d_out;
  float* ws  = (float*)d_ws;

  // zero flags + bf16 h double buffers each replay (partial fully overwritten)
  (void)hipMemsetAsync(d_ws, 0, (size_t)(WS_HX + 524288) * 4, stream);

  uproj_kernel<<<dim3(256), dim3(256), 0, stream>>>(
      u, w_in, (unsigned short*)(ws + WS_UPROJ));
  esn_kernel<<<dim3(512), dim3(512), 0, stream>>>(w, w_bias, w_out, ws);
  combine_kernel<<<dim3((BB * TT * OO) / 256), dim3(256), 0, stream>>>(
      w_out, ws + WS_PART, out);
}

// Round 20
// 387.550 us; speedup vs baseline: 1.2318x; 1.0728x over previous
//
#include <hip/hip_runtime.h>

#define BB 8
#define TT 2048
#define DD 64
#define HH 1024
#define OO 16
#define NGRP 16
#define RB 16          // row-blocks per sub-group
#define CHSG 16        // chains per sub-group (2 sub-groups -> 32 chains/group)
#define CHUNK 64
#define WASH 24
#define STEPS (CHUNK + WASH)   // 88
#define ZPS 20         // zp stride: 2-way banks (free) on write AND finalize read

typedef __attribute__((ext_vector_type(8))) short short8;
typedef __attribute__((ext_vector_type(4))) float f32x4;

// ws layout (f32 units)
#define WS_FLAGS 0                        // [grp][half][pb][cb] x32 u32 = 262144
#define WS_HX    262144                   // [grp][half][par][ch][HH] bf16 = 524288 f32
#define WS_UPROJ (WS_HX + 524288)         // [b][t][HH] bf16 = 8388608 f32
#define WS_PART  (WS_UPROJ + 8388608)     // [grp][rb][TT][OO] f32 = 8388608

#define FLAG_IDX(g, h, pb, cb) (((((g)*2 + (h)) * RB + (pb)) * RB + (cb)) * 32)

__device__ __forceinline__ unsigned short f2bf(float x) {
  union { float f; unsigned u; } v; v.f = x;
  unsigned r = v.u + 0x7FFF + ((v.u >> 16) & 1);   // RNE
  return (unsigned short)(r >> 16);
}
__device__ __forceinline__ float bf2f(unsigned short h) {
  union { unsigned u; float f; } v; v.u = ((unsigned)h) << 16; return v.f;
}

// proven r11 protocol: ALL exchange ops sc0 sc1 (served at the coherence point)
__device__ __forceinline__ uint4 ld_cohx4(const void* p) {
  uint4 r;
  asm volatile("global_load_dwordx4 %0, %1, off sc0 sc1" : "=&v"(r) : "v"(p));
  return r;
}
__device__ __forceinline__ void st_coh(unsigned* p, unsigned v) {
  asm volatile("global_store_dword %0, %1, off sc0 sc1" :: "v"(p), "v"(v) : "memory");
}
__device__ __forceinline__ unsigned ld_flag(const unsigned* p) {
  unsigned r;
  asm volatile("global_load_dword %0, %1, off sc0 sc1\n\ts_waitcnt vmcnt(0)"
               : "=&v"(r) : "v"(p) : "memory");
  return r;
}

__device__ __forceinline__ short8 ld_bf16x8(const float* p) {
  float4 v0 = *(const float4*)p;
  float4 v1 = *(const float4*)(p + 4);
  short8 r;
  r[0] = (short)f2bf(v0.x); r[1] = (short)f2bf(v0.y);
  r[2] = (short)f2bf(v0.z); r[3] = (short)f2bf(v0.w);
  r[4] = (short)f2bf(v1.x); r[5] = (short)f2bf(v1.y);
  r[6] = (short)f2bf(v1.z); r[7] = (short)f2bf(v1.w);
  return r;
}

// prep GEMM: up[bt][row] = w_in[row,:] . u[bt,:]  (M=16384, N=1024, K=64, MFMA)
__global__ __launch_bounds__(256) void uproj_kernel(
    const float* __restrict__ u, const float* __restrict__ w_in,
    unsigned short* __restrict__ up) {
  const int tid = threadIdx.x;
  const int lane = tid & 63;
  const int wv = tid >> 6;
  const int lm = lane & 15;
  const int l4 = lane >> 4;
  const int bt0 = blockIdx.x * 64;

  short8 A[4][2];
#pragma unroll
  for (int btt = 0; btt < 4; ++btt)
#pragma unroll
    for (int kt = 0; kt < 2; ++kt)
      A[btt][kt] = ld_bf16x8(u + (size_t)(bt0 + btt * 16 + lm) * DD + kt * 32 + l4 * 8);

#pragma unroll 1
  for (int rt = wv; rt < 64; rt += 4) {
    const float* wp = w_in + (size_t)(rt * 16 + lm) * DD + l4 * 8;
    short8 B0 = ld_bf16x8(wp);
    short8 B1 = ld_bf16x8(wp + 32);
#pragma unroll
    for (int btt = 0; btt < 4; ++btt) {
      f32x4 acc = (f32x4){0.f, 0.f, 0.f, 0.f};
      acc = __builtin_amdgcn_mfma_f32_16x16x32_bf16(A[btt][0], B0, acc, 0, 0, 0);
      acc = __builtin_amdgcn_mfma_f32_16x16x32_bf16(A[btt][1], B1, acc, 0, 0, 0);
#pragma unroll
      for (int j = 0; j < 4; ++j) {
        int bt = bt0 + btt * 16 + l4 * 4 + j;
        up[(size_t)bt * HH + rt * 16 + lm] = f2bf(acc[j]);
      }
    }
  }
}

__global__ __launch_bounds__(512, 4) void esn_kernel(
    const float* __restrict__ w, const float* __restrict__ w_bias,
    const float* __restrict__ w_out, float* __restrict__ ws)
{
  __shared__ float zp_sh[8 * 64 * ZPS];  // [wave][row*ZPS + ch]  (40 KB)
  __shared__ float hn_sh[64 * 17];       // [row*17 + ch]
  __shared__ float wout_sh[64 * 17];     // [row*17 + o]

  const int tid = threadIdx.x;
  const int lane = tid & 63;
  const int rg = tid >> 6;            // wave 0..7, k-slice [rg*128, rg*128+128)
  const int lm = lane & 15;
  const int l4 = lane >> 4;
  const int bid = blockIdx.x;
  const int grp = bid & 15;           // group = dir*8 + b
  const int rb = (bid >> 4) & 15;     // row-block: rows [rb*64, rb*64+64)
  const int half = bid >> 8;          // sub-group 0/1 (chains half*16..+16)
  const int dir = grp >> 3;
  const int b = grp & 7;
  const int row0 = rb * 64;

  unsigned* flags = (unsigned*)ws;
  unsigned short* hx = (unsigned short*)(ws + WS_HX);
  const unsigned short* uproj = (const unsigned short*)(ws + WS_UPROJ);
  float* partial = ws + WS_PART;

  // ---- A fragments, hi-only bf16: rows row0+mt*16+lm, k=(rg*4+kt)*32+l4*8+j
  short8 Ahi[4][4];
#pragma unroll
  for (int mt = 0; mt < 4; ++mt) {
#pragma unroll
    for (int kt = 0; kt < 4; ++kt)
      Ahi[mt][kt] = ld_bf16x8(
          w + (size_t)(row0 + mt * 16 + lm) * HH + (rg * 4 + kt) * 32 + l4 * 8);
  }

  for (int idx = tid; idx < 1024; idx += 512) {
    int r = idx >> 4, o = idx & 15;
    wout_sh[r * 17 + o] = w_out[(size_t)(1 + dir * HH + row0 + r) * OO + o];
  }

  // finalize mapping: thread -> chain ch, rows 2q2, 2q2+1
  const int ch = tid & 15;
  const int q2 = tid >> 4;            // 0..31
  const float bias0 = w_bias[row0 + 2 * q2];
  const float bias1 = w_bias[row0 + 2 * q2 + 1];
  const int cc_g = half * CHSG + ch;
  int ts_f = cc_g * CHUNK - WASH; if (ts_f < 0) ts_f = 0;
  float hp0 = 0.f, hp1 = 0.f;
  __syncthreads();

#pragma unroll 1
  for (int i = 0; i < STEPS; ++i) {
    const int par = i & 1;
    const unsigned short* hb_r =
        hx + ((size_t)((grp * 2 + half) * 2 + par) * CHSG + lm) * HH;

    // ---- uproj load early (plain cached; latency hides under poll+MFMA)
    int tau_f = ts_f + i;
    int t_u = dir ? (TT - 1 - tau_f) : tau_f;
    unsigned up = *(const unsigned*)(uproj + (size_t)(b * TT + t_u) * HH + row0 + 2 * q2);

    // ---- per-wave producer-pair poll (r17-proven): blocks 2rg, 2rg+1 of own half
    if (i > 0) {
      const unsigned tg = (unsigned)i;
      unsigned v;
      do {
        v = 0xFFFFFFFFu;
        if (lane < 2)
          v = ld_flag(flags + FLAG_IDX(grp, half, 2 * rg + lane, rb));
      } while (!__all(v >= tg));
      asm volatile("" ::: "memory");
    }

    // ---- B loads: own k-slice, 4 coherent dwordx4 (hi-only bf16 h)
    uint4 Bv[4];
#pragma unroll
    for (int kt = 0; kt < 4; ++kt)
      Bv[kt] = ld_cohx4(hb_r + (rg * 4 + kt) * 32 + l4 * 8);
    asm volatile("s_waitcnt vmcnt(0)" ::: "memory");
    __builtin_amdgcn_sched_barrier(0);

    f32x4 acc[4];
#pragma unroll
    for (int mt = 0; mt < 4; ++mt) acc[mt] = (f32x4){0.f, 0.f, 0.f, 0.f};
#pragma unroll
    for (int kt = 0; kt < 4; ++kt) {
      short8 bh = *(short8*)&Bv[kt];
#pragma unroll
      for (int mt = 0; mt < 4; ++mt)
        acc[mt] = __builtin_amdgcn_mfma_f32_16x16x32_bf16(Ahi[mt][kt], bh, acc[mt], 0, 0, 0);
    }

    // ---- per-wave K-partials to LDS (stride 20: 2-way banks, free)
#pragma unroll
    for (int mt = 0; mt < 4; ++mt)
#pragma unroll
      for (int j = 0; j < 4; ++j)
        zp_sh[rg * (64 * ZPS) + (mt * 16 + l4 * 4 + j) * ZPS + lm] = acc[mt][j];
    __syncthreads();

    // ---- finalize rows 2q2, 2q2+1 of chain ch
    float z0 = bias0 + bf2f((unsigned short)(up & 0xFFFFu));
    float z1 = bias1 + bf2f((unsigned short)(up >> 16));
#pragma unroll
    for (int g2 = 0; g2 < 8; ++g2) {
      z0 += zp_sh[g2 * (64 * ZPS) + (2 * q2) * ZPS + ch];
      z1 += zp_sh[g2 * (64 * ZPS) + (2 * q2 + 1) * ZPS + ch];
    }
    float e0 = __expf(2.f * z0), e1 = __expf(2.f * z1);
    float th0 = 1.f - 2.f * __builtin_amdgcn_rcpf(e0 + 1.f);
    float th1 = 1.f - 2.f * __builtin_amdgcn_rcpf(e1 + 1.f);
    hp0 = 0.1f * hp0 + 0.9f * th0;
    hp1 = 0.1f * hp1 + 0.9f * th1;
    hn_sh[(2 * q2) * 17 + ch] = hp0;
    hn_sh[(2 * q2 + 1) * 17 + ch] = hp1;
    unsigned pv = (unsigned)f2bf(hp0) | ((unsigned)f2bf(hp1) << 16);
    unsigned short* hw =
        hx + ((size_t)((grp * 2 + half) * 2 + (par ^ 1)) * CHSG + ch) * HH;
    st_coh((unsigned*)(hw + row0 + 2 * q2), pv);
    asm volatile("s_waitcnt vmcnt(0)" ::: "memory");   // h at coherence point
    __syncthreads();                                   // all waves' h committed
    if (tid < 16)   // replicated flag: one line per consumer block (r17-proven)
      st_coh(flags + FLAG_IDX(grp, half, rb, tid), (unsigned)(i + 1));

    // ---- readout: 2 chains per wave, direct writes (disjoint t)
#pragma unroll
    for (int cidx = 0; cidx < 2; ++cidx) {
      int cc = rg * 2 + cidx;               // local chain
      int cg = half * CHSG + cc;            // global chain
      int ts = cg * CHUNK - WASH; if (ts < 0) ts = 0;
      int tau = ts + i;
      int rel = tau - cg * CHUNK;
      if (rel >= 0 && rel < CHUNK) {
        int t_out = dir ? (TT - 1 - tau) : tau;
        float s = 0.f;
#pragma unroll
        for (int j = 0; j < 16; ++j)
          s += hn_sh[(l4 * 16 + j) * 17 + cc] * wout_sh[(l4 * 16 + j) * 17 + lm];
        s += __shfl_xor(s, 16);
        s += __shfl_xor(s, 32);
        if (lane < 16)
          partial[((size_t)(grp * RB + rb) * TT + t_out) * OO + lm] = s;
      }
    }
  }
}

__global__ __launch_bounds__(256) void combine_kernel(
    const float* __restrict__ w_out, const float* __restrict__ partial,
    float* __restrict__ out)
{
  int idx = blockIdx.x * 256 + threadIdx.x;   // (b*2048+t)*16+o
  int o = idx & 15;
  int bt = idx >> 4;
  int b_ = bt >> 11;
  int t_ = bt & 2047;
  float s = w_out[o];   // bias row
#pragma unroll 1
  for (int dir = 0; dir < 2; ++dir)
#pragma unroll
    for (int g = 0; g < 16; ++g)
      s += partial[((size_t)((dir * 8 + b_) * 16 + g) * TT + t_) * OO + o];
  out[idx] = s;
}

extern "C" void kernel_launch(void* const* d_in, const int* in_sizes, int n_in,
                              void* d_out, int out_size, void* d_ws, size_t ws_size,
                              hipStream_t stream) {
  (void)in_sizes; (void)n_in; (void)out_size; (void)ws_size;
  const float* u      = (const float*)d_in[0];
  const float* w      = (const float*)d_in[1];
  const float* w_in   = (const float*)d_in[2];
  const float* w_bias = (const float*)d_in[3];
  const float* w_out  = (const float*)d_in[4];
  float* out = (float*)d_out;
  float* ws  = (float*)d_ws;

  // zero flags + bf16 h double buffers each replay (partial fully overwritten)
  (void)hipMemsetAsync(d_ws, 0, (size_t)(WS_HX + 524288) * 4, stream);

  uproj_kernel<<<dim3(256), dim3(256), 0, stream>>>(
      u, w_in, (unsigned short*)(ws + WS_UPROJ));
  esn_kernel<<<dim3(512), dim3(512), 0, stream>>>(w, w_bias, w_out, ws);
  combine_kernel<<<dim3((BB * TT * OO) / 256), dim3(256), 0, stream>>>(
      w_out, ws + WS_PART, out);
}